// Round 20
// baseline (77.331 us; speedup 1.0000x reference)
//
#include <hip/hip_runtime.h>
#include <math.h>

#define EPS 1e-8f
#define NN 65536
#define MAGIC 1.0f

// ws float offsets
#define WS_GATES 0       // 2048
#define WS_HNEW  2048    // 512
#define WS_ROUT  2560    // 518 (pad 520)
#define WS_PMAX  3104    // 2048
#define WS_PEXP  5152    // 2048
#define WS_S     7200    // 65536
#define WS_PART  72992   // 256*512 (k_out stage-1 output)
#define WS_FLAGG 204064  // 128
#define WS_FLAGP 204192  // 256
#define WS_PART2 204448  // 32*512
#define WS_FLAG2 220832  // 32
#define WS_FLAGR 220864  // 130
#define WS_BF    262144  // fp8 shadow: 65536*512*1B = 32 MB
#define WS_PARTB 17039360 // 2048*512 floats (4 MB)
#define WS_PSUMB 18087936 // 2048

typedef float f32x2 __attribute__((ext_vector_type(2)));

__device__ __forceinline__ float wave_sum(float v) {
    for (int o = 32; o > 0; o >>= 1) v += __shfl_xor(v, o);
    return v;
}
__device__ __forceinline__ float sigm(float x) { return 1.f / (1.f + expf(-x)); }
__device__ __forceinline__ float softplusf_(float x) {
    return x > 20.f ? x : log1pf(expf(x));
}
__device__ __forceinline__ float dot4(float4 a, float4 b) {
    return a.x * b.x + a.y * b.y + a.z * b.z + a.w * b.w;
}
__device__ __forceinline__ float4 ld4(const float* p) { return *(const float4*)p; }

// agent-scope accessors. RULE (R18): never ACQUIRE inside a spin loop —
// each agent-acquire emits an L2 invalidate. Poll RELAXED, ONE fence after.
__device__ __forceinline__ float ald(const float* p) {
    return __hip_atomic_load(p, __ATOMIC_RELAXED, __HIP_MEMORY_SCOPE_AGENT);
}
__device__ __forceinline__ void ast(float* p, float v) {
    __hip_atomic_store(p, v, __ATOMIC_RELAXED, __HIP_MEMORY_SCOPE_AGENT);
}
__device__ __forceinline__ void ast_rel(float* p, float v) {
    __hip_atomic_store(p, v, __ATOMIC_RELEASE, __HIP_MEMORY_SCOPE_AGENT);
}
__device__ __forceinline__ void acq_fence() {
    __builtin_amdgcn_fence(__ATOMIC_ACQUIRE, "agent");
}

// fp8 e4m3 (OCP) pack via gfx950 HW converters
__device__ __forceinline__ unsigned pk8(float4 v) {
    int u = __builtin_amdgcn_cvt_pk_fp8_f32(v.x, v.y, 0, false);
    u = __builtin_amdgcn_cvt_pk_fp8_f32(v.z, v.w, u, true);
    return (unsigned)u;
}

// ==== K_A: front (gates -> h_new/r_out) fused into cos via RELAXED flags ====
__global__ __launch_bounds__(256) void k_fc(const float* __restrict__ x,
                                            const float* __restrict__ pr,
                                            const float* __restrict__ h,
                                            const float* __restrict__ c,
                                            const float* __restrict__ W_ih,
                                            const float* __restrict__ b_ih,
                                            const float* __restrict__ W_hh,
                                            const float* __restrict__ b_hh,
                                            const float* __restrict__ W_read,
                                            const float* __restrict__ b_read,
                                            const float* __restrict__ mem,
                                            float* __restrict__ ws) {
    const int b = blockIdx.x, t = threadIdx.x;
    const int lane = t & 63, wv = t >> 6;
    __shared__ float sh[512];

    // ---- front phase A: gates (blocks 0-127, 16 rows each) ----
    if (b < 128) {
        #pragma unroll
        for (int i = 0; i < 4; ++i) {
            const int row = b * 16 + wv * 4 + i;
            const float* wi = W_ih + (size_t)row * 768;
            const float* wh = W_hh + (size_t)row * 512;
            float acc = dot4(ld4(wi + lane * 4), ld4(x + lane * 4))
                      + dot4(ld4(wi + 256 + lane * 4), ld4(pr + lane * 4))
                      + dot4(ld4(wi + 512 + lane * 4), ld4(pr + 256 + lane * 4))
                      + dot4(ld4(wh + lane * 4), ld4(h + lane * 4))
                      + dot4(ld4(wh + 256 + lane * 4), ld4(h + 256 + lane * 4));
            acc = wave_sum(acc);
            if (lane == 0) ast(ws + WS_GATES + row, acc + b_ih[row] + b_hh[row]);
        }
        __syncthreads();
        if (t == 0) ast_rel(ws + WS_FLAGG + b, MAGIC);
    }

    // ---- front phase B: h_new + r_out (blocks 0-129) ----
    if (b < 130) {
        if (wv == 0) {
            int cap = 0;
            for (;;) {
                float v0 = ald(ws + WS_FLAGG + lane);
                float v1 = ald(ws + WS_FLAGG + 64 + lane);
                if (__all(v0 == MAGIC && v1 == MAGIC)) break;
                __builtin_amdgcn_s_sleep(1);
                if (++cap > (1 << 20)) break;
            }
            acq_fence();
        }
        __syncthreads();
        for (int j = t; j < 512; j += 256) {
            float ig = ald(ws + WS_GATES + j);
            float fg = ald(ws + WS_GATES + 512 + j);
            float gg = ald(ws + WS_GATES + 1024 + j);
            float og = ald(ws + WS_GATES + 1536 + j);
            float cn = sigm(fg) * c[j] + sigm(ig) * tanhf(gg);
            float hn = sigm(og) * tanhf(cn);
            sh[j] = hn;
            if (b == 0) ws[WS_HNEW + j] = hn;
        }
        __syncthreads();
        const int o = b * 4 + wv;
        if (o < 518) {
            const float* wr = W_read + (size_t)o * 512;
            float acc = dot4(ld4(wr + lane * 4), ld4(sh + lane * 4))
                      + dot4(ld4(wr + 256 + lane * 4), ld4(sh + 256 + lane * 4));
            acc = wave_sum(acc);
            if (lane == 0) ws[WS_ROUT + o] = acc + b_read[o];
        }
        __syncthreads();
        if (t == 0) ast_rel(ws + WS_FLAGR + b, MAGIC);
    }

    // ---- all blocks: wait for full ROUT (130 flags, RELAXED poll) ----
    if (wv == 0) {
        int cap = 0;
        for (;;) {
            float v0 = ald(ws + WS_FLAGR + lane);
            float v1 = ald(ws + WS_FLAGR + 64 + lane);
            float v2 = ald(ws + WS_FLAGR + 128 + (lane & 1));
            if (__all(v0 == MAGIC && v1 == MAGIC && v2 == MAGIC)) break;
            __builtin_amdgcn_s_sleep(1);
            if (++cap > (1 << 20)) break;
        }
        acq_fence();
    }
    __syncthreads();

    // ---- cos + fp8 shadow (R19 body) ----
    const int gw = b * 4 + wv;
    const float* key = ws + WS_ROUT;
    unsigned char* wsb = (unsigned char*)(ws + WS_BF);
    float4 ka = ld4(key + lane * 4);
    float4 kb = ld4(key + 256 + lane * 4);
    ka.x += EPS; ka.y += EPS; ka.z += EPS; ka.w += EPS;
    kb.x += EPS; kb.y += EPS; kb.z += EPS; kb.w += EPS;
    const float nb = fmaxf(__builtin_amdgcn_sqrtf(
                        wave_sum(dot4(ka, ka) + dot4(kb, kb))), EPS);
    const float beta = softplusf_(key[512]);
    float* sp = ws + WS_S;

    float4 va[4], vb[4], xa[4], xb[4];
    #pragma unroll
    for (int i = 0; i < 4; ++i) {
        const size_t n = (size_t)gw + i * 8192;
        va[i] = ld4(mem + n * 512 + lane * 4);
        vb[i] = ld4(mem + n * 512 + 256 + lane * 4);
    }
    #pragma unroll
    for (int i = 0; i < 4; ++i) {
        const size_t n = (size_t)gw + (4 + i) * 8192;
        xa[i] = ld4(mem + n * 512 + lane * 4);
        xb[i] = ld4(mem + n * 512 + 256 + lane * 4);
    }

    float m = -1e30f, e = 0.f;
    #pragma unroll
    for (int grp = 0; grp < 2; ++grp) {
        float d[4], q[4];
        #pragma unroll
        for (int i = 0; i < 4; ++i) {
            const size_t n = (size_t)gw + (grp * 4 + i) * 8192;
            *(unsigned*)(wsb + n * 512 + lane * 4) = pk8(va[i]);
            *(unsigned*)(wsb + n * 512 + 256 + lane * 4) = pk8(vb[i]);
            float4 wa = va[i], wb = vb[i];
            wa.x += EPS; wa.y += EPS; wa.z += EPS; wa.w += EPS;
            wb.x += EPS; wb.y += EPS; wb.z += EPS; wb.w += EPS;
            d[i] = dot4(wa, ka) + dot4(wb, kb);
            q[i] = dot4(wa, wa) + dot4(wb, wb);
        }
        if (grp == 0) {
            #pragma unroll
            for (int i = 0; i < 4; ++i) { va[i] = xa[i]; vb[i] = xb[i]; }
        }
        #pragma unroll
        for (int o = 32; o > 0; o >>= 1) {
            #pragma unroll
            for (int i = 0; i < 4; ++i) {
                d[i] += __shfl_xor(d[i], o);
                q[i] += __shfl_xor(q[i], o);
            }
        }
        float sv[4];
        #pragma unroll
        for (int i = 0; i < 4; ++i) {
            float na = fmaxf(__builtin_amdgcn_sqrtf(q[i]), EPS);
            sv[i] = beta * d[i] * __builtin_amdgcn_rcpf(na * nb);
        }
        float mysv = sv[0];
        if (lane == 1) mysv = sv[1];
        if (lane == 2) mysv = sv[2];
        if (lane == 3) mysv = sv[3];
        if (lane < 4) sp[gw + (grp * 4 + lane) * 8192] = mysv;
        float gm = fmaxf(fmaxf(sv[0], sv[1]), fmaxf(sv[2], sv[3]));
        float nm = fmaxf(m, gm);
        e = e * __expf(m - nm) + __expf(sv[0] - nm) + __expf(sv[1] - nm)
          + __expf(sv[2] - nm) + __expf(sv[3] - nm);
        m = nm;
    }

    __shared__ float sm[4], se[4];
    if (lane == 0) { sm[wv] = m; se[wv] = e; }
    __syncthreads();
    if (t == 0) {
        float M = fmaxf(fmaxf(sm[0], sm[1]), fmaxf(sm[2], sm[3]));
        float E = se[0] * __expf(sm[0] - M) + se[1] * __expf(sm[1] - M) +
                  se[2] * __expf(sm[2] - M) + se[3] * __expf(sm[3] - M);
        ws[WS_PMAX + b] = M;
        ws[WS_PEXP + b] = E;
    }
}

// K3: high-occupancy col-sum over the FP8 shadow (R19, unchanged)
__global__ __launch_bounds__(256) void k_read(const float* __restrict__ rs,
                                              float* __restrict__ ws) {
    const int bb = blockIdx.x, t = threadIdx.x;
    const int lane = t & 63, wv = t >> 6;
    __shared__ float s_m[4], s_e[4];
    __shared__ float wi_l[34];
    __shared__ float pl[32];
    __shared__ float sacc[3][512];

    float m = -1e30f, e = 0.f;
    #pragma unroll
    for (int i = 0; i < 8; ++i) {
        float bm = ws[WS_PMAX + t + 256 * i], be = ws[WS_PEXP + t + 256 * i];
        float nm = fmaxf(m, bm);
        e = e * __expf(m - nm) + be * __expf(bm - nm);
        m = nm;
    }
    for (int o = 32; o > 0; o >>= 1) {
        float om = __shfl_xor(m, o), oe = __shfl_xor(e, o);
        float nm = fmaxf(m, om);
        e = e * __expf(m - nm) + oe * __expf(om - nm);
        m = nm;
    }
    if (lane == 0) { s_m[wv] = m; s_e[wv] = e; }
    __syncthreads();
    const float mx = fmaxf(fmaxf(s_m[0], s_m[1]), fmaxf(s_m[2], s_m[3]));
    const float Z = s_e[0] * __expf(s_m[0] - mx) + s_e[1] * __expf(s_m[1] - mx)
                  + s_e[2] * __expf(s_m[2] - mx) + s_e[3] * __expf(s_m[3] - mx);
    const float invZ = 1.f / Z;
    const float g = sigm(ws[WS_ROUT + 513]);
    float a3 = ws[WS_ROUT + 514], b3 = ws[WS_ROUT + 515], c3 = ws[WS_ROUT + 516];
    float mm = fmaxf(a3, fmaxf(b3, c3));
    float ea = __expf(a3 - mm), eb = __expf(b3 - mm), ec = __expf(c3 - mm);
    float ss = ea + eb + ec;
    const float s0 = ea / ss, s1 = eb / ss, s2 = ec / ss;
    const float gamma = 1.f + softplusf_(ws[WS_ROUT + 517]);

    const int start = bb * 32;
    if (t < 34) {
        int idx = (start - 1 + t) & (NN - 1);
        wi_l[t] = g * rs[idx] + (1.f - g) * __expf(ws[WS_S + idx] - mx) * invZ;
    }
    __syncthreads();
    float ps = 0.f;
    if (t < 32) {
        float wsh = wi_l[t] * s0 + wi_l[t + 1] * s1 + wi_l[t + 2] * s2;
        float pv = __powf(wsh, gamma);
        pl[t] = pv;
        ps = pv;
    }
    ps = wave_sum(ps);
    if (t == 0) ws[WS_PSUMB + bb] = ps;
    __syncthreads();

    const unsigned char* slab =
        (const unsigned char*)(ws + WS_BF) + (size_t)(start + wv * 8) * 512;
    float a0 = 0.f, a1 = 0.f, a2 = 0.f, a3f = 0.f,
          a4 = 0.f, a5 = 0.f, a6 = 0.f, a7 = 0.f;
    #pragma unroll
    for (int r = 0; r < 8; ++r) {
        float w = pl[wv * 8 + r];
        uint2 q = *(const uint2*)(slab + (size_t)r * 512 + lane * 8);
        f32x2 f0 = __builtin_amdgcn_cvt_pk_f32_fp8(q.x, false);
        f32x2 f1 = __builtin_amdgcn_cvt_pk_f32_fp8(q.x, true);
        f32x2 f2 = __builtin_amdgcn_cvt_pk_f32_fp8(q.y, false);
        f32x2 f3 = __builtin_amdgcn_cvt_pk_f32_fp8(q.y, true);
        a0 += w * f0.x;  a1 += w * f0.y;
        a2 += w * f1.x;  a3f += w * f1.y;
        a4 += w * f2.x;  a5 += w * f2.y;
        a6 += w * f3.x;  a7 += w * f3.y;
    }
    if (wv) {
        float* sw = sacc[wv - 1];
        sw[0 * 64 + lane] = a0; sw[1 * 64 + lane] = a1;
        sw[2 * 64 + lane] = a2; sw[3 * 64 + lane] = a3f;
        sw[4 * 64 + lane] = a4; sw[5 * 64 + lane] = a5;
        sw[6 * 64 + lane] = a6; sw[7 * 64 + lane] = a7;
    }
    __syncthreads();
    if (!wv) {
        #pragma unroll
        for (int i = 0; i < 3; ++i) {
            const float* sw = sacc[i];
            a0 += sw[0 * 64 + lane]; a1 += sw[1 * 64 + lane];
            a2 += sw[2 * 64 + lane]; a3f += sw[3 * 64 + lane];
            a4 += sw[4 * 64 + lane]; a5 += sw[5 * 64 + lane];
            a6 += sw[6 * 64 + lane]; a7 += sw[7 * 64 + lane];
        }
        float* pp = ws + WS_PARTB + (size_t)bb * 512 + lane * 8;
        *(float4*)pp = make_float4(a0, a1, a2, a3f);
        *(float4*)(pp + 4) = make_float4(a4, a5, a6, a7);
    }
}

// K4: tree-reduce PARTB(2048) -> 256 -> 32 -> rd; Zp; W_out matvec (R19)
__global__ __launch_bounds__(512) void k_out(const float* __restrict__ W_out,
                                             const float* __restrict__ b_out,
                                             float* __restrict__ ws,
                                             float* __restrict__ out) {
    const int b = blockIdx.x, t = threadIdx.x;
    const int lane = t & 63, wv = t >> 6;
    __shared__ float rd[512];
    __shared__ float s_z[8];

    {
        float s = 0.f;
        #pragma unroll
        for (int r = 0; r < 8; ++r)
            s += ws[WS_PARTB + (size_t)(8 * b + r) * 512 + t];
        ws[WS_PART + (size_t)b * 512 + t] = s;
    }
    __syncthreads();
    if (t == 0) ast_rel(ws + WS_FLAGP + b, MAGIC);
    if (b >= 32) return;

    if (wv == 0) {
        int cap = 0;
        for (;;) {
            float v0 = ald(ws + WS_FLAGP + lane);
            float v1 = ald(ws + WS_FLAGP + 64 + lane);
            float v2 = ald(ws + WS_FLAGP + 128 + lane);
            float v3 = ald(ws + WS_FLAGP + 192 + lane);
            if (__all(v0 == MAGIC && v1 == MAGIC && v2 == MAGIC && v3 == MAGIC))
                break;
            __builtin_amdgcn_s_sleep(1);
            if (++cap > (1 << 20)) break;
        }
        acq_fence();
    }
    __syncthreads();
    {
        float s = 0.f;
        #pragma unroll
        for (int r = 0; r < 8; ++r)
            s += ws[WS_PART + (size_t)(8 * b + r) * 512 + t];
        ws[WS_PART2 + (size_t)b * 512 + t] = s;
    }
    __syncthreads();
    if (t == 0) ast_rel(ws + WS_FLAG2 + b, MAGIC);
    if (wv == 0) {
        int cap = 0;
        for (;;) {
            float v = ald(ws + WS_FLAG2 + (lane & 31));
            if (__all(v == MAGIC)) break;
            __builtin_amdgcn_s_sleep(1);
            if (++cap > (1 << 20)) break;
        }
        acq_fence();
    }
    __syncthreads();
    float z = 0.f;
    #pragma unroll
    for (int i = 0; i < 4; ++i) z += ws[WS_PSUMB + t + 512 * i];
    z = wave_sum(z);
    if (lane == 0) s_z[wv] = z;
    __syncthreads();
    float Zp = 0.f;
    for (int i = 0; i < 8; ++i) Zp += s_z[i];
    const float invZp = 1.f / (Zp + EPS);
    {
        float s = 0.f;
        #pragma unroll
        for (int r = 0; r < 32; ++r)
            s += ws[WS_PART2 + (size_t)r * 512 + t];
        rd[t] = s * invZp;
    }
    __syncthreads();
    const int o = b * 8 + wv;
    const float* wo = W_out + (size_t)o * 1024;
    float a = dot4(ld4(wo + lane * 4), ld4(ws + WS_HNEW + lane * 4))
            + dot4(ld4(wo + 256 + lane * 4), ld4(ws + WS_HNEW + 256 + lane * 4))
            + dot4(ld4(wo + 512 + lane * 4), ld4(rd + lane * 4))
            + dot4(ld4(wo + 768 + lane * 4), ld4(rd + 256 + lane * 4));
    a = wave_sum(a);
    if (lane == 0) out[o] = sigm(a + b_out[o]);
}

extern "C" void kernel_launch(void* const* d_in, const int* in_sizes, int n_in,
                              void* d_out, int out_size, void* d_ws, size_t ws_size,
                              hipStream_t stream) {
    const float* x          = (const float*)d_in[0];
    const float* memory     = (const float*)d_in[1];
    const float* prev_read  = (const float*)d_in[2];
    const float* h          = (const float*)d_in[3];
    const float* c          = (const float*)d_in[4];
    const float* read_state = (const float*)d_in[5];
    // d_in[6] write_state, d_in[13] W_write, d_in[14] b_write: dead in reference
    const float* W_ih   = (const float*)d_in[7];
    const float* b_ih   = (const float*)d_in[8];
    const float* W_hh   = (const float*)d_in[9];
    const float* b_hh   = (const float*)d_in[10];
    const float* W_read = (const float*)d_in[11];
    const float* b_read = (const float*)d_in[12];
    const float* W_out  = (const float*)d_in[15];
    const float* b_out  = (const float*)d_in[16];
    float* ws  = (float*)d_ws;
    float* out = (float*)d_out;

    k_fc<<<2048, 256, 0, stream>>>(x, prev_read, h, c, W_ih, b_ih, W_hh, b_hh,
                                   W_read, b_read, memory, ws);
    k_read<<<2048, 256, 0, stream>>>(read_state, ws);
    k_out<<<256, 512, 0, stream>>>(W_out, b_out, ws, out);
}

// Round 21
// 64.813 us; speedup vs baseline: 1.1932x; 1.1932x over previous
//
#include <hip/hip_runtime.h>
#include <math.h>

#define EPS 1e-8f
#define NN 65536
#define MAGIC 1.0f

// ws float offsets (R17/R19 layout)
#define WS_GATES 0       // 2048
#define WS_HNEW  2048    // 512
#define WS_ROUT  2560    // 518 (pad 520)
#define WS_PMAX  3104    // 2048
#define WS_PEXP  5152    // 2048
#define WS_S     7200    // 65536
#define WS_PART  72992   // 256*512 (k_out stage-1 output)
#define WS_FLAGG 204064  // 128
#define WS_FLAGP 204192  // 256
#define WS_PART2 204448  // 32*512
#define WS_FLAG2 220832  // 32
#define WS_BF    262144  // fp8 shadow: 65536*512*1B = 32 MB
#define WS_PARTB 17039360 // 2048*512 floats (4 MB)
#define WS_PSUMB 18087936 // 2048

typedef float f32x2 __attribute__((ext_vector_type(2)));

__device__ __forceinline__ float wave_sum(float v) {
    for (int o = 32; o > 0; o >>= 1) v += __shfl_xor(v, o);
    return v;
}
__device__ __forceinline__ float sigm(float x) { return 1.f / (1.f + expf(-x)); }
__device__ __forceinline__ float softplusf_(float x) {
    return x > 20.f ? x : log1pf(expf(x));
}
__device__ __forceinline__ float dot4(float4 a, float4 b) {
    return a.x * b.x + a.y * b.y + a.z * b.z + a.w * b.w;
}
__device__ __forceinline__ float4 ld4(const float* p) { return *(const float4*)p; }

// agent-scope accessors. RULE (R18): never ACQUIRE inside a spin loop —
// each agent-acquire emits an L2 invalidate. Poll RELAXED, ONE fence after.
// RULE (R20): never let thousands of blocks poll — flag lines are uncached
// cross-XCD; poller count must stay O(100).
__device__ __forceinline__ float ald(const float* p) {
    return __hip_atomic_load(p, __ATOMIC_RELAXED, __HIP_MEMORY_SCOPE_AGENT);
}
__device__ __forceinline__ void ast(float* p, float v) {
    __hip_atomic_store(p, v, __ATOMIC_RELAXED, __HIP_MEMORY_SCOPE_AGENT);
}
__device__ __forceinline__ void ast_rel(float* p, float v) {
    __hip_atomic_store(p, v, __ATOMIC_RELEASE, __HIP_MEMORY_SCOPE_AGENT);
}
__device__ __forceinline__ void acq_fence() {
    __builtin_amdgcn_fence(__ATOMIC_ACQUIRE, "agent");
}

// fp8 e4m3 (OCP) pack/unpack via gfx950 HW converters
__device__ __forceinline__ unsigned pk8(float4 v) {
    int u = __builtin_amdgcn_cvt_pk_fp8_f32(v.x, v.y, 0, false);
    u = __builtin_amdgcn_cvt_pk_fp8_f32(v.z, v.w, u, true);
    return (unsigned)u;
}

// K1: gates (blocks 0-127, 16 rows each) -> flag -> h_new + r_out
__global__ __launch_bounds__(256) void k_front(const float* __restrict__ x,
                                               const float* __restrict__ pr,
                                               const float* __restrict__ h,
                                               const float* __restrict__ c,
                                               const float* __restrict__ W_ih,
                                               const float* __restrict__ b_ih,
                                               const float* __restrict__ W_hh,
                                               const float* __restrict__ b_hh,
                                               const float* __restrict__ W_read,
                                               const float* __restrict__ b_read,
                                               float* __restrict__ ws) {
    const int b = blockIdx.x, t = threadIdx.x;
    const int lane = t & 63, wv = t >> 6;
    __shared__ float sh[512];

    if (b < 128) {
        #pragma unroll
        for (int i = 0; i < 4; ++i) {
            const int row = b * 16 + wv * 4 + i;
            const float* wi = W_ih + (size_t)row * 768;
            const float* wh = W_hh + (size_t)row * 512;
            float acc = dot4(ld4(wi + lane * 4), ld4(x + lane * 4))
                      + dot4(ld4(wi + 256 + lane * 4), ld4(pr + lane * 4))
                      + dot4(ld4(wi + 512 + lane * 4), ld4(pr + 256 + lane * 4))
                      + dot4(ld4(wh + lane * 4), ld4(h + lane * 4))
                      + dot4(ld4(wh + 256 + lane * 4), ld4(h + 256 + lane * 4));
            acc = wave_sum(acc);
            if (lane == 0) ast(ws + WS_GATES + row, acc + b_ih[row] + b_hh[row]);
        }
        __syncthreads();
        if (t == 0) ast_rel(ws + WS_FLAGG + b, MAGIC);
    }

    if (wv == 0) {
        int cap = 0;
        for (;;) {
            float v0 = ald(ws + WS_FLAGG + lane);          // RELAXED poll
            float v1 = ald(ws + WS_FLAGG + 64 + lane);
            if (__all(v0 == MAGIC && v1 == MAGIC)) break;
            __builtin_amdgcn_s_sleep(1);
            if (++cap > (1 << 20)) break;
        }
        acq_fence();                                        // ONE invalidate
    }
    __syncthreads();

    for (int j = t; j < 512; j += 256) {
        float ig = ald(ws + WS_GATES + j);
        float fg = ald(ws + WS_GATES + 512 + j);
        float gg = ald(ws + WS_GATES + 1024 + j);
        float og = ald(ws + WS_GATES + 1536 + j);
        float cn = sigm(fg) * c[j] + sigm(ig) * tanhf(gg);
        float hn = sigm(og) * tanhf(cn);
        sh[j] = hn;
        if (b == 0) ws[WS_HNEW + j] = hn;
    }
    __syncthreads();
    const int o = b * 4 + wv;
    if (o < 518) {
        const float* wr = W_read + (size_t)o * 512;
        float acc = dot4(ld4(wr + lane * 4), ld4(sh + lane * 4))
                  + dot4(ld4(wr + 256 + lane * 4), ld4(sh + 256 + lane * 4));
        acc = wave_sum(acc);
        if (lane == 0) ws[WS_ROUT + o] = acc + b_read[o];
    }
}

// K2: cosine + FP8 shadow (software-pipelined, at-wire)
__global__ __launch_bounds__(256) void k_cos(const float* __restrict__ mem,
                                             float* __restrict__ ws) {
    const int t = threadIdx.x, lane = t & 63, wv = t >> 6;
    const int gw = blockIdx.x * 4 + wv;
    const float* key = ws + WS_ROUT;
    unsigned char* wsb = (unsigned char*)(ws + WS_BF);
    float4 ka = ld4(key + lane * 4);
    float4 kb = ld4(key + 256 + lane * 4);
    ka.x += EPS; ka.y += EPS; ka.z += EPS; ka.w += EPS;
    kb.x += EPS; kb.y += EPS; kb.z += EPS; kb.w += EPS;
    const float nb = fmaxf(__builtin_amdgcn_sqrtf(
                        wave_sum(dot4(ka, ka) + dot4(kb, kb))), EPS);
    const float beta = softplusf_(key[512]);
    float* sp = ws + WS_S;

    float4 va[4], vb[4], xa[4], xb[4];
    #pragma unroll
    for (int i = 0; i < 4; ++i) {
        const size_t n = (size_t)gw + i * 8192;
        va[i] = ld4(mem + n * 512 + lane * 4);
        vb[i] = ld4(mem + n * 512 + 256 + lane * 4);
    }
    #pragma unroll
    for (int i = 0; i < 4; ++i) {
        const size_t n = (size_t)gw + (4 + i) * 8192;
        xa[i] = ld4(mem + n * 512 + lane * 4);
        xb[i] = ld4(mem + n * 512 + 256 + lane * 4);
    }

    float m = -1e30f, e = 0.f;
    #pragma unroll
    for (int grp = 0; grp < 2; ++grp) {
        float d[4], q[4];
        #pragma unroll
        for (int i = 0; i < 4; ++i) {
            const size_t n = (size_t)gw + (grp * 4 + i) * 8192;
            *(unsigned*)(wsb + n * 512 + lane * 4) = pk8(va[i]);
            *(unsigned*)(wsb + n * 512 + 256 + lane * 4) = pk8(vb[i]);
            float4 wa = va[i], wb = vb[i];
            wa.x += EPS; wa.y += EPS; wa.z += EPS; wa.w += EPS;
            wb.x += EPS; wb.y += EPS; wb.z += EPS; wb.w += EPS;
            d[i] = dot4(wa, ka) + dot4(wb, kb);
            q[i] = dot4(wa, wa) + dot4(wb, wb);
        }
        if (grp == 0) {
            #pragma unroll
            for (int i = 0; i < 4; ++i) { va[i] = xa[i]; vb[i] = xb[i]; }
        }
        #pragma unroll
        for (int o = 32; o > 0; o >>= 1) {
            #pragma unroll
            for (int i = 0; i < 4; ++i) {
                d[i] += __shfl_xor(d[i], o);
                q[i] += __shfl_xor(q[i], o);
            }
        }
        float sv[4];
        #pragma unroll
        for (int i = 0; i < 4; ++i) {
            float na = fmaxf(__builtin_amdgcn_sqrtf(q[i]), EPS);
            sv[i] = beta * d[i] * __builtin_amdgcn_rcpf(na * nb);
        }
        float mysv = sv[0];
        if (lane == 1) mysv = sv[1];
        if (lane == 2) mysv = sv[2];
        if (lane == 3) mysv = sv[3];
        if (lane < 4) sp[gw + (grp * 4 + lane) * 8192] = mysv;
        float gm = fmaxf(fmaxf(sv[0], sv[1]), fmaxf(sv[2], sv[3]));
        float nm = fmaxf(m, gm);
        e = e * __expf(m - nm) + __expf(sv[0] - nm) + __expf(sv[1] - nm)
          + __expf(sv[2] - nm) + __expf(sv[3] - nm);
        m = nm;
    }

    __shared__ float sm[4], se[4];
    if (lane == 0) { sm[wv] = m; se[wv] = e; }
    __syncthreads();
    if (t == 0) {
        float M = fmaxf(fmaxf(sm[0], sm[1]), fmaxf(sm[2], sm[3]));
        float E = se[0] * __expf(sm[0] - M) + se[1] * __expf(sm[1] - M) +
                  se[2] * __expf(sm[2] - M) + se[3] * __expf(sm[3] - M);
        ws[WS_PMAX + blockIdx.x] = M;
        ws[WS_PEXP + blockIdx.x] = E;
    }
}

// K3: high-occupancy col-sum over the FP8 shadow
__global__ __launch_bounds__(256) void k_read(const float* __restrict__ rs,
                                              float* __restrict__ ws) {
    const int bb = blockIdx.x, t = threadIdx.x;
    const int lane = t & 63, wv = t >> 6;
    __shared__ float s_m[4], s_e[4];
    __shared__ float wi_l[34];
    __shared__ float pl[32];
    __shared__ float sacc[3][512];

    float m = -1e30f, e = 0.f;
    #pragma unroll
    for (int i = 0; i < 8; ++i) {
        float bm = ws[WS_PMAX + t + 256 * i], be = ws[WS_PEXP + t + 256 * i];
        float nm = fmaxf(m, bm);
        e = e * __expf(m - nm) + be * __expf(bm - nm);
        m = nm;
    }
    for (int o = 32; o > 0; o >>= 1) {
        float om = __shfl_xor(m, o), oe = __shfl_xor(e, o);
        float nm = fmaxf(m, om);
        e = e * __expf(m - nm) + oe * __expf(om - nm);
        m = nm;
    }
    if (lane == 0) { s_m[wv] = m; s_e[wv] = e; }
    __syncthreads();
    const float mx = fmaxf(fmaxf(s_m[0], s_m[1]), fmaxf(s_m[2], s_m[3]));
    const float Z = s_e[0] * __expf(s_m[0] - mx) + s_e[1] * __expf(s_m[1] - mx)
                  + s_e[2] * __expf(s_m[2] - mx) + s_e[3] * __expf(s_m[3] - mx);
    const float invZ = 1.f / Z;
    const float g = sigm(ws[WS_ROUT + 513]);
    float a3 = ws[WS_ROUT + 514], b3 = ws[WS_ROUT + 515], c3 = ws[WS_ROUT + 516];
    float mm = fmaxf(a3, fmaxf(b3, c3));
    float ea = __expf(a3 - mm), eb = __expf(b3 - mm), ec = __expf(c3 - mm);
    float ss = ea + eb + ec;
    const float s0 = ea / ss, s1 = eb / ss, s2 = ec / ss;
    const float gamma = 1.f + softplusf_(ws[WS_ROUT + 517]);

    const int start = bb * 32;
    if (t < 34) {
        int idx = (start - 1 + t) & (NN - 1);
        wi_l[t] = g * rs[idx] + (1.f - g) * __expf(ws[WS_S + idx] - mx) * invZ;
    }
    __syncthreads();
    float ps = 0.f;
    if (t < 32) {
        float wsh = wi_l[t] * s0 + wi_l[t + 1] * s1 + wi_l[t + 2] * s2;
        float pv = __powf(wsh, gamma);
        pl[t] = pv;
        ps = pv;
    }
    ps = wave_sum(ps);
    if (t == 0) ws[WS_PSUMB + bb] = ps;
    __syncthreads();

    const unsigned char* slab =
        (const unsigned char*)(ws + WS_BF) + (size_t)(start + wv * 8) * 512;
    float a0 = 0.f, a1 = 0.f, a2 = 0.f, a3f = 0.f,
          a4 = 0.f, a5 = 0.f, a6 = 0.f, a7 = 0.f;
    #pragma unroll
    for (int r = 0; r < 8; ++r) {
        float w = pl[wv * 8 + r];
        uint2 q = *(const uint2*)(slab + (size_t)r * 512 + lane * 8);
        f32x2 f0 = __builtin_amdgcn_cvt_pk_f32_fp8(q.x, false);
        f32x2 f1 = __builtin_amdgcn_cvt_pk_f32_fp8(q.x, true);
        f32x2 f2 = __builtin_amdgcn_cvt_pk_f32_fp8(q.y, false);
        f32x2 f3 = __builtin_amdgcn_cvt_pk_f32_fp8(q.y, true);
        a0 += w * f0.x;  a1 += w * f0.y;
        a2 += w * f1.x;  a3f += w * f1.y;
        a4 += w * f2.x;  a5 += w * f2.y;
        a6 += w * f3.x;  a7 += w * f3.y;
    }
    if (wv) {
        float* sw = sacc[wv - 1];
        sw[0 * 64 + lane] = a0; sw[1 * 64 + lane] = a1;
        sw[2 * 64 + lane] = a2; sw[3 * 64 + lane] = a3f;
        sw[4 * 64 + lane] = a4; sw[5 * 64 + lane] = a5;
        sw[6 * 64 + lane] = a6; sw[7 * 64 + lane] = a7;
    }
    __syncthreads();
    if (!wv) {
        #pragma unroll
        for (int i = 0; i < 3; ++i) {
            const float* sw = sacc[i];
            a0 += sw[0 * 64 + lane]; a1 += sw[1 * 64 + lane];
            a2 += sw[2 * 64 + lane]; a3f += sw[3 * 64 + lane];
            a4 += sw[4 * 64 + lane]; a5 += sw[5 * 64 + lane];
            a6 += sw[6 * 64 + lane]; a7 += sw[7 * 64 + lane];
        }
        float* pp = ws + WS_PARTB + (size_t)bb * 512 + lane * 8;
        *(float4*)pp = make_float4(a0, a1, a2, a3f);
        *(float4*)(pp + 4) = make_float4(a4, a5, a6, a7);
    }
}

// K4: tree-reduce PARTB(2048) -> 256 -> 32 -> rd; Zp; W_out matvec.
__global__ __launch_bounds__(512) void k_out(const float* __restrict__ W_out,
                                             const float* __restrict__ b_out,
                                             float* __restrict__ ws,
                                             float* __restrict__ out) {
    const int b = blockIdx.x, t = threadIdx.x;
    const int lane = t & 63, wv = t >> 6;
    __shared__ float rd[512];
    __shared__ float s_z[8];

    {
        float s = 0.f;
        #pragma unroll
        for (int r = 0; r < 8; ++r)
            s += ws[WS_PARTB + (size_t)(8 * b + r) * 512 + t];
        ws[WS_PART + (size_t)b * 512 + t] = s;
    }
    __syncthreads();
    if (t == 0) ast_rel(ws + WS_FLAGP + b, MAGIC);
    if (b >= 32) return;

    if (wv == 0) {
        int cap = 0;
        for (;;) {
            float v0 = ald(ws + WS_FLAGP + lane);
            float v1 = ald(ws + WS_FLAGP + 64 + lane);
            float v2 = ald(ws + WS_FLAGP + 128 + lane);
            float v3 = ald(ws + WS_FLAGP + 192 + lane);
            if (__all(v0 == MAGIC && v1 == MAGIC && v2 == MAGIC && v3 == MAGIC))
                break;
            __builtin_amdgcn_s_sleep(1);
            if (++cap > (1 << 20)) break;
        }
        acq_fence();
    }
    __syncthreads();
    {
        float s = 0.f;
        #pragma unroll
        for (int r = 0; r < 8; ++r)
            s += ws[WS_PART + (size_t)(8 * b + r) * 512 + t];
        ws[WS_PART2 + (size_t)b * 512 + t] = s;
    }
    __syncthreads();
    if (t == 0) ast_rel(ws + WS_FLAG2 + b, MAGIC);
    if (wv == 0) {
        int cap = 0;
        for (;;) {
            float v = ald(ws + WS_FLAG2 + (lane & 31));
            if (__all(v == MAGIC)) break;
            __builtin_amdgcn_s_sleep(1);
            if (++cap > (1 << 20)) break;
        }
        acq_fence();
    }
    __syncthreads();
    float z = 0.f;
    #pragma unroll
    for (int i = 0; i < 4; ++i) z += ws[WS_PSUMB + t + 512 * i];
    z = wave_sum(z);
    if (lane == 0) s_z[wv] = z;
    __syncthreads();
    float Zp = 0.f;
    for (int i = 0; i < 8; ++i) Zp += s_z[i];
    const float invZp = 1.f / (Zp + EPS);
    {
        float s = 0.f;
        #pragma unroll
        for (int r = 0; r < 32; ++r)
            s += ws[WS_PART2 + (size_t)r * 512 + t];
        rd[t] = s * invZp;
    }
    __syncthreads();
    const int o = b * 8 + wv;
    const float* wo = W_out + (size_t)o * 1024;
    float a = dot4(ld4(wo + lane * 4), ld4(ws + WS_HNEW + lane * 4))
            + dot4(ld4(wo + 256 + lane * 4), ld4(ws + WS_HNEW + 256 + lane * 4))
            + dot4(ld4(wo + 512 + lane * 4), ld4(rd + lane * 4))
            + dot4(ld4(wo + 768 + lane * 4), ld4(rd + 256 + lane * 4));
    a = wave_sum(a);
    if (lane == 0) out[o] = sigm(a + b_out[o]);
}

extern "C" void kernel_launch(void* const* d_in, const int* in_sizes, int n_in,
                              void* d_out, int out_size, void* d_ws, size_t ws_size,
                              hipStream_t stream) {
    const float* x          = (const float*)d_in[0];
    const float* memory     = (const float*)d_in[1];
    const float* prev_read  = (const float*)d_in[2];
    const float* h          = (const float*)d_in[3];
    const float* c          = (const float*)d_in[4];
    const float* read_state = (const float*)d_in[5];
    // d_in[6] write_state, d_in[13] W_write, d_in[14] b_write: dead in reference
    const float* W_ih   = (const float*)d_in[7];
    const float* b_ih   = (const float*)d_in[8];
    const float* W_hh   = (const float*)d_in[9];
    const float* b_hh   = (const float*)d_in[10];
    const float* W_read = (const float*)d_in[11];
    const float* b_read = (const float*)d_in[12];
    const float* W_out  = (const float*)d_in[15];
    const float* b_out  = (const float*)d_in[16];
    float* ws  = (float*)d_ws;
    float* out = (float*)d_out;

    k_front<<<130, 256, 0, stream>>>(x, prev_read, h, c, W_ih, b_ih, W_hh, b_hh,
                                     W_read, b_read, ws);
    k_cos<<<2048, 256, 0, stream>>>(memory, ws);
    k_read<<<2048, 256, 0, stream>>>(read_state, ws);
    k_out<<<256, 512, 0, stream>>>(W_out, b_out, ws, out);
}